// Round 7
// baseline (189.239 us; speedup 1.0000x reference)
//
#include <hip/hip_runtime.h>
#include <cmath>
#include <cstdint>

#define NB 32
#define NI 512
#define NT 4096
#define NSTEPS (NT - 2)   // 4094
#define THR 512           // threads per k_scan block
#define SPT 8             // steps per thread (512*8 = 4096 >= 4094)
#define GBLK 4096         // k_gather grid (flat linear sweep — round-5 lesson:
                          // tiling breaks the GPU-wide sequential DRAM sweep)
#define GITER 16          // quads per thread: 16.7M / (4096*256)

// ---------------------------------------------------------------------------
// JAX threefry2x32 (20 rounds), matches jax/_src/prng.py exactly.
// Verified bit-exact on hardware (rounds 1-6: absmax 0.0).
// ---------------------------------------------------------------------------
__device__ __forceinline__ uint32_t rotl32(uint32_t v, unsigned d) {
  return (v << d) | (v >> (32u - d));
}

__device__ __forceinline__ void threefry2x32(uint32_t k0, uint32_t k1,
                                             uint32_t& x0, uint32_t& x1) {
  const uint32_t k2 = k0 ^ k1 ^ 0x1BD11BDAu;
  x0 += k0; x1 += k1;
#define TF_R(rot) { x0 += x1; x1 = rotl32(x1, rot); x1 ^= x0; }
  TF_R(13) TF_R(15) TF_R(26) TF_R(6)
  x0 += k1; x1 += k2 + 1u;
  TF_R(17) TF_R(29) TF_R(16) TF_R(24)
  x0 += k2; x1 += k0 + 2u;
  TF_R(13) TF_R(15) TF_R(26) TF_R(6)
  x0 += k0; x1 += k1 + 3u;
  TF_R(17) TF_R(29) TF_R(16) TF_R(24)
  x0 += k1; x1 += k2 + 4u;
  TF_R(13) TF_R(15) TF_R(26) TF_R(6)
  x0 += k2; x1 += k0 + 5u;
#undef TF_R
}

// uniform(minval=tiny,maxval=1) -> gumbel, f32 rounding after each log
// (emulated via correctly-rounded double log). Verified bit-exact.
__device__ __forceinline__ float gumbel_from_bits(uint32_t bits) {
  uint32_t fb = (bits >> 9) | 0x3F800000u;
  float f = __uint_as_float(fb) - 1.0f;          // [0, 1)
  float u = fmaxf(f, __FLT_MIN__);               // jnp.finfo(f32).tiny
  float lg = (float)log((double)u);
  return -(float)log((double)(-lg));
}

// ---------------------------------------------------------------------------
// 4-state chain encoding: 0:(p1=0) 1:(p1=1) 2:(p1=2,spec=0) 3:(p1=2,spec=1).
// Step: s = (st==3) ? sB : sA;  st' = (st==1 && s==2) ? 3 : s.
// Map over 4 states packed 2 bits/state in low 8 bits of a u32.
// ---------------------------------------------------------------------------
__device__ __forceinline__ uint32_t comp_map(uint32_t a, uint32_t b) {
  uint32_t r = 0;
#pragma unroll
  for (int st = 0; st < 4; ++st) {
    uint32_t as = (a >> (2 * st)) & 3u;
    uint32_t bs = (b >> (2 * as)) & 3u;
    r |= bs << (2 * st);
  }
  return r;
}

// ---------------------------------------------------------------------------
// K1: per (t,b) sample pair (sA: generic row [LP,LS,LP]; sB: special row
// [-inf,LB1,LB2]) via partitionable threefry split + gumbel argmax.
// AGENT-scope stores (cross-XCD visibility under graph replay — round-1
// lesson: intra-graph kernel boundaries do NOT provide L2 maintenance).
// Spread over ALL CUs (round-3 lesson: packed into 32 blocks costs ~55 us).
// Measured ~3 us total together with k_scan (round-5 decomposition).
// ---------------------------------------------------------------------------
__global__ void k_sab(uint32_t* __restrict__ sab32,
                      float LP, float LS, float LB1, float LB2) {
  int t = blockIdx.x * blockDim.x + threadIdx.x;
  int b = blockIdx.y;
  if (t >= NSTEPS) return;
  uint32_t k0 = 0u, k1 = (uint32_t)t;
  threefry2x32(0u, 42u, k0, k1);                 // key_t
  float g[3];
#pragma unroll
  for (int j = 0; j < 3; ++j) {
    uint32_t x0 = 0u, x1 = (uint32_t)(3 * b + j);
    threefry2x32(k0, k1, x0, x1);
    g[j] = gumbel_from_bits(x0 ^ x1);
  }
  float vA0 = LP + g[0], vA1 = LS + g[1], vA2 = LP + g[2];
  int sA = 0; float m = vA0;
  if (vA1 > m) { m = vA1; sA = 1; }
  if (vA2 > m) { sA = 2; }
  int sB = (LB2 + g[2] > LB1 + g[1]) ? 2 : 1;    // j=0 logit is -inf
  uint32_t v = (uint32_t)(sA | (sB << 4));
  __hip_atomic_store(&sab32[(size_t)b * NT + t], v,
                     __ATOMIC_RELAXED, __HIP_MEMORY_SCOPE_AGENT);
}

// ---------------------------------------------------------------------------
// K2: one block per batch — 4-state function-composition scan (9 LDS rounds),
// replay, cooperative AGENT-scope stores of packed m words.
// ---------------------------------------------------------------------------
__global__ void __launch_bounds__(THR) k_scan(uint32_t* __restrict__ sab32,
                                              uint32_t* __restrict__ mword) {
  const int b = blockIdx.x;
  const int tid = threadIdx.x;

  __shared__ uint32_t smap[THR];
  __shared__ uint8_t lds_m[NT];

  // ---- load my SPT sab entries (pack nibbles) ----
  uint32_t packA = 0, packB = 0;
  const uint32_t* src = sab32 + (size_t)b * NT;
#pragma unroll
  for (int k = 0; k < SPT; ++k) {
    int t = tid * SPT + k;
    if (t >= NSTEPS) break;
    uint32_t w = __hip_atomic_load(&src[t], __ATOMIC_RELAXED,
                                   __HIP_MEMORY_SCOPE_AGENT);
    packA |= (w & 0xFu) << (4 * k);
    packB |= ((w >> 4) & 0xFu) << (4 * k);
  }

  // ---- build my chunk map ----
  uint32_t cmap;
  {
    uint32_t st0 = 0, st1 = 1, st2 = 2, st3 = 3;
#pragma unroll
    for (int k = 0; k < SPT; ++k) {
      int t = tid * SPT + k;
      if (t >= NSTEPS) break;
      uint32_t sA = (packA >> (4 * k)) & 0xFu;
      uint32_t sB = (packB >> (4 * k)) & 0xFu;
#define STEP(st) { uint32_t s = (st == 3u) ? sB : sA; st = (st == 1u && s == 2u) ? 3u : s; }
      STEP(st0) STEP(st1) STEP(st2) STEP(st3)
#undef STEP
    }
    cmap = st0 | (st1 << 2) | (st2 << 4) | (st3 << 6);
  }
  smap[tid] = cmap;
  __syncthreads();
  for (int d = 1; d < THR; d <<= 1) {
    uint32_t prev = (tid >= d) ? smap[tid - d] : 0u;
    __syncthreads();
    if (tid >= d) smap[tid] = comp_map(prev, smap[tid]);
    __syncthreads();
  }
  uint32_t st = (tid == 0) ? 1u : ((smap[tid - 1] >> 2) & 3u);

  // ---- replay, write m bytes ----
#pragma unroll
  for (int k = 0; k < SPT; ++k) {
    int t = tid * SPT + k;
    if (t >= NSTEPS) break;
    uint32_t sA = (packA >> (4 * k)) & 0xFu;
    uint32_t sB = (packB >> (4 * k)) & 0xFu;
    uint32_t s = (st == 3u) ? sB : sA;
    st = (st == 1u && s == 2u) ? 3u : s;
    lds_m[t + 1] = (uint8_t)s;
  }
  if (tid == 0) lds_m[0] = 1;
  if (tid == THR - 1) lds_m[NT - 1] = 1;
  __syncthreads();

  const uint32_t* wsrc = (const uint32_t*)lds_m;
  uint32_t* dst = mword + (size_t)b * (NT / 4);
#pragma unroll
  for (int r = 0; r < (NT / 4) / THR; ++r) {
    int w = r * THR + tid;
    __hip_atomic_store(&dst[w], wsrc[w],
                       __ATOMIC_RELAXED, __HIP_MEMORY_SCOPE_AGENT);
  }
}

// ---------------------------------------------------------------------------
// K3: gather out[b,i,t] = x[b,i, m[b,t] + t - 1].
// FLAT linear-sweep mapping (round-5 lesson: tiles destroy the GPU-wide
// sequential DRAM sweep). In this mapping, per block the 16 grid-stride
// iterations share (i, t, w) and vary only b = b0 + 2k — so the block's
// entire mword need (16 x 256 words = 16 KB) is cooperatively AGENT-loaded
// into LDS up front: all 16 loads per thread issue back-to-back (latency
// paid once, overlapped), and the hot loop's index source is an LDS hit.
// Round-6 lesson: doing this hoist into REGISTERS cost VGPR 32->60 and
// occupancy 53->38% and regressed; LDS keeps VGPR ~flat, 8 blocks/CU.
// ---------------------------------------------------------------------------
__global__ void __launch_bounds__(256) k_gather(const float* __restrict__ x,
                                                uint32_t* __restrict__ mword,
                                                float* __restrict__ out) {
  const int tid = threadIdx.x;
  const int blk = blockIdx.x;

  __shared__ uint32_t lds_mw[GITER * 256];       // 16 KB

  const int w  = ((blk & 3) << 8) | tid;         // mword col, const over k
  const int b0 = blk >> 11;                      // 0 or 1; b_k = b0 + 2k
#pragma unroll
  for (int k = 0; k < GITER; ++k) {
    lds_mw[k * 256 + tid] = __hip_atomic_load(
        &mword[((size_t)(b0 + 2 * k) << 10) | (uint32_t)w],
        __ATOMIC_RELAXED, __HIP_MEMORY_SCOPE_AGENT);
  }
  __syncthreads();

  const int q0  = blk * 256 + tid;
  const int rem = q0 & ((1 << 19) - 1);          // const over k
  const int i   = rem >> 10;
  const int t   = (rem & 1023) << 2;

#pragma unroll 4
  for (int k = 0; k < GITER; ++k) {
    const int b = b0 + 2 * k;
    const uint32_t mw = lds_mw[k * 256 + tid];
    const size_t row = ((size_t)b * NI + i) << 12;
    const float* xb = x + row;
    float4 o;
    o.x = xb[(int)( mw        & 0xFFu) + t + 0 - 1];
    o.y = xb[(int)((mw >>  8) & 0xFFu) + t + 1 - 1];
    o.z = xb[(int)((mw >> 16) & 0xFFu) + t + 2 - 1];
    o.w = xb[(int)((mw >> 24) & 0xFFu) + t + 3 - 1];
    *(float4*)(out + row + t) = o;
  }
}

// ---------------------------------------------------------------------------
extern "C" void kernel_launch(void* const* d_in, const int* in_sizes, int n_in,
                              void* d_out, int out_size, void* d_ws, size_t ws_size,
                              hipStream_t stream) {
  const float* x = (const float*)d_in[0];
  float* out = (float*)d_out;

  uint8_t* ws = (uint8_t*)d_ws;
  uint32_t* sab32 = (uint32_t*)ws;               // 32*4096*4 = 524288 B
  uint32_t* mword = (uint32_t*)(ws + 524288);    // 32*1024*4 = 131072 B

  const double pd = 0.1, sd = 1.0 - 2.0 * 0.1;
  const float pf = (float)pd, sf = (float)sd;
  const float b1 = (float)(sd / (pd + sd));
  const float b2 = (float)(pd / (pd + sd));
  const float LP  = (float)log((double)pf);
  const float LS  = (float)log((double)sf);
  const float LB1 = (float)log((double)b1);
  const float LB2 = (float)log((double)b2);

  dim3 g1((NSTEPS + 255) / 256, NB);
  k_sab<<<g1, 256, 0, stream>>>(sab32, LP, LS, LB1, LB2);
  k_scan<<<NB, THR, 0, stream>>>(sab32, mword);
  k_gather<<<GBLK, 256, 0, stream>>>(x, mword, out);
}

// Round 8
// 159.875 us; speedup vs baseline: 1.1837x; 1.1837x over previous
//
#include <hip/hip_runtime.h>
#include <cmath>
#include <cstdint>

#define NB 32
#define NI 512
#define NT 4096
#define NSTEPS (NT - 2)   // 4094
#define THR 512           // threads per k_scan block
#define SPT 8             // steps per thread (512*8 = 4096 >= 4094)
#define GBLK 4096         // k_gather grid (flat linear sweep — round-5 lesson:
                          // tiling breaks the GPU-wide sequential DRAM sweep)
#define GITER 16          // quads per thread: 16.7M / (4096*256)
#define NCOPY 8           // P replication (de-hotspot the coherence point)

// ---------------------------------------------------------------------------
// JAX threefry2x32 (20 rounds), matches jax/_src/prng.py exactly.
// Verified bit-exact on hardware (rounds 1-7: absmax 0.0).
// ---------------------------------------------------------------------------
__device__ __forceinline__ uint32_t rotl32(uint32_t v, unsigned d) {
  return (v << d) | (v >> (32u - d));
}

__device__ __forceinline__ void threefry2x32(uint32_t k0, uint32_t k1,
                                             uint32_t& x0, uint32_t& x1) {
  const uint32_t k2 = k0 ^ k1 ^ 0x1BD11BDAu;
  x0 += k0; x1 += k1;
#define TF_R(rot) { x0 += x1; x1 = rotl32(x1, rot); x1 ^= x0; }
  TF_R(13) TF_R(15) TF_R(26) TF_R(6)
  x0 += k1; x1 += k2 + 1u;
  TF_R(17) TF_R(29) TF_R(16) TF_R(24)
  x0 += k2; x1 += k0 + 2u;
  TF_R(13) TF_R(15) TF_R(26) TF_R(6)
  x0 += k0; x1 += k1 + 3u;
  TF_R(17) TF_R(29) TF_R(16) TF_R(24)
  x0 += k1; x1 += k2 + 4u;
  TF_R(13) TF_R(15) TF_R(26) TF_R(6)
  x0 += k2; x1 += k0 + 5u;
#undef TF_R
}

// uniform(minval=tiny,maxval=1) -> gumbel, f32 rounding after each log
// (emulated via correctly-rounded double log). Verified bit-exact.
__device__ __forceinline__ float gumbel_from_bits(uint32_t bits) {
  uint32_t fb = (bits >> 9) | 0x3F800000u;
  float f = __uint_as_float(fb) - 1.0f;          // [0, 1)
  float u = fmaxf(f, __FLT_MIN__);               // jnp.finfo(f32).tiny
  float lg = (float)log((double)u);
  return -(float)log((double)(-lg));
}

// ---------------------------------------------------------------------------
// 4-state chain encoding: 0:(p1=0) 1:(p1=1) 2:(p1=2,spec=0) 3:(p1=2,spec=1).
// Step: s = (st==3) ? sB : sA;  st' = (st==1 && s==2) ? 3 : s.
// ---------------------------------------------------------------------------
__device__ __forceinline__ uint32_t comp_map(uint32_t a, uint32_t b) {
  uint32_t r = 0;
#pragma unroll
  for (int st = 0; st < 4; ++st) {
    uint32_t as = (a >> (2 * st)) & 3u;
    uint32_t bs = (b >> (2 * as)) & 3u;
    r |= bs << (2 * st);
  }
  return r;
}

// ---------------------------------------------------------------------------
// K1: per (t,b) sample pair via partitionable threefry split + gumbel argmax.
// AGENT-scope stores (cross-XCD visibility under graph replay — round-1
// lesson). Spread over ALL CUs (round-3 lesson). ~3 us with k_scan.
// ---------------------------------------------------------------------------
__global__ void k_sab(uint32_t* __restrict__ sab32,
                      float LP, float LS, float LB1, float LB2) {
  int t = blockIdx.x * blockDim.x + threadIdx.x;
  int b = blockIdx.y;
  if (t >= NSTEPS) return;
  uint32_t k0 = 0u, k1 = (uint32_t)t;
  threefry2x32(0u, 42u, k0, k1);                 // key_t
  float g[3];
#pragma unroll
  for (int j = 0; j < 3; ++j) {
    uint32_t x0 = 0u, x1 = (uint32_t)(3 * b + j);
    threefry2x32(k0, k1, x0, x1);
    g[j] = gumbel_from_bits(x0 ^ x1);
  }
  float vA0 = LP + g[0], vA1 = LS + g[1], vA2 = LP + g[2];
  int sA = 0; float m = vA0;
  if (vA1 > m) { m = vA1; sA = 1; }
  if (vA2 > m) { sA = 2; }
  int sB = (LB2 + g[2] > LB1 + g[1]) ? 2 : 1;    // j=0 logit is -inf
  uint32_t v = (uint32_t)(sA | (sB << 4));
  __hip_atomic_store(&sab32[(size_t)b * NT + t], v,
                     __ATOMIC_RELAXED, __HIP_MEMORY_SCOPE_AGENT);
}

// ---------------------------------------------------------------------------
// K2: one block per batch — 4-state function-composition scan (9 LDS rounds),
// replay into lds_m, then emit the PACKED-TRANSPOSED table P (NCOPY copies).
// P layout (16B groups): P[c][b0][w] bytes k=0..15, where byte k packs the
// 4 m-values (2 bits each) of batch b = b0 + 2k at t-quad w. A gather thread
// reads its whole 16-iteration index stream as ONE 16B group (2 u64 loads).
// Each batch-block writes byte k of every group — distinct bytes, no races;
// every byte rewritten each call (replay-safe).
// ---------------------------------------------------------------------------
__global__ void __launch_bounds__(THR) k_scan(uint32_t* __restrict__ sab32,
                                              uint8_t* __restrict__ P) {
  const int b = blockIdx.x;
  const int tid = threadIdx.x;

  __shared__ uint32_t smap[THR];
  __shared__ uint8_t lds_m[NT];

  // ---- load my SPT sab entries (pack nibbles) ----
  uint32_t packA = 0, packB = 0;
  const uint32_t* src = sab32 + (size_t)b * NT;
#pragma unroll
  for (int k = 0; k < SPT; ++k) {
    int t = tid * SPT + k;
    if (t >= NSTEPS) break;
    uint32_t w = __hip_atomic_load(&src[t], __ATOMIC_RELAXED,
                                   __HIP_MEMORY_SCOPE_AGENT);
    packA |= (w & 0xFu) << (4 * k);
    packB |= ((w >> 4) & 0xFu) << (4 * k);
  }

  // ---- build my chunk map ----
  uint32_t cmap;
  {
    uint32_t st0 = 0, st1 = 1, st2 = 2, st3 = 3;
#pragma unroll
    for (int k = 0; k < SPT; ++k) {
      int t = tid * SPT + k;
      if (t >= NSTEPS) break;
      uint32_t sA = (packA >> (4 * k)) & 0xFu;
      uint32_t sB = (packB >> (4 * k)) & 0xFu;
#define STEP(st) { uint32_t s = (st == 3u) ? sB : sA; st = (st == 1u && s == 2u) ? 3u : s; }
      STEP(st0) STEP(st1) STEP(st2) STEP(st3)
#undef STEP
    }
    cmap = st0 | (st1 << 2) | (st2 << 4) | (st3 << 6);
  }
  smap[tid] = cmap;
  __syncthreads();
  for (int d = 1; d < THR; d <<= 1) {
    uint32_t prev = (tid >= d) ? smap[tid - d] : 0u;
    __syncthreads();
    if (tid >= d) smap[tid] = comp_map(prev, smap[tid]);
    __syncthreads();
  }
  uint32_t st = (tid == 0) ? 1u : ((smap[tid - 1] >> 2) & 3u);

  // ---- replay, write m bytes ----
#pragma unroll
  for (int k = 0; k < SPT; ++k) {
    int t = tid * SPT + k;
    if (t >= NSTEPS) break;
    uint32_t sA = (packA >> (4 * k)) & 0xFu;
    uint32_t sB = (packB >> (4 * k)) & 0xFu;
    uint32_t s = (st == 3u) ? sB : sA;
    st = (st == 1u && s == 2u) ? 3u : s;
    lds_m[t + 1] = (uint8_t)s;
  }
  if (tid == 0) lds_m[0] = 1;
  if (tid == THR - 1) lds_m[NT - 1] = 1;
  __syncthreads();

  // ---- emit packed-transposed P: byte (b>>1) of group (b&1, w), x NCOPY ----
  const int b0 = b & 1;
  const int kk = b >> 1;                         // byte index within group
#pragma unroll
  for (int r = 0; r < (NT / 4) / THR; ++r) {     // 2 rounds: w = tid, tid+512
    int w = r * THR + tid;
    uint8_t pb = (uint8_t)( (uint32_t)lds_m[4 * w]
                          | ((uint32_t)lds_m[4 * w + 1] << 2)
                          | ((uint32_t)lds_m[4 * w + 2] << 4)
                          | ((uint32_t)lds_m[4 * w + 3] << 6));
    size_t goff = ((size_t)((b0 << 10) | w) << 4) + kk;
#pragma unroll
    for (int c = 0; c < NCOPY; ++c) {
      __hip_atomic_store(&P[((size_t)c << 15) + goff], pb,
                         __ATOMIC_RELAXED, __HIP_MEMORY_SCOPE_AGENT);
    }
  }
}

// ---------------------------------------------------------------------------
// K3: gather out[b,i,t] = x[b,i, m[b,t] + t - 1].
// EXACT round-4 structure (flat linear sweep, per-thread, no barrier, no LDS
// — rounds 5/6/7 lesson: tiling, register-hoist, and LDS-hoist all regress).
// Change vs round 4: the 16 per-iteration u32 agent loads are replaced by
// TWO u64 agent loads of the packed-transposed P group (4x less coherence
// traffic, 16 -> 2 latency exposures, +~6 VGPR), read from copy blk&7
// (spreads the coherence-point hot region 8x).
// ---------------------------------------------------------------------------
__global__ void __launch_bounds__(256) k_gather(const float* __restrict__ x,
                                                const uint8_t* __restrict__ P,
                                                float* __restrict__ out) {
  const int q0  = blockIdx.x * 256 + threadIdx.x;
  const int b0  = q0 >> 19;                      // 0 or 1; b_k = b0 + 2k
  const int rem = q0 & ((1 << 19) - 1);          // const over k
  const int i   = rem >> 10;
  const int w   = rem & 1023;
  const int t   = w << 2;

  const uint8_t* Pc = P + ((size_t)(blockIdx.x & (NCOPY - 1)) << 15)
                        + ((size_t)((b0 << 10) | w) << 4);
  const uint64_t plo = __hip_atomic_load((const uint64_t*)Pc,
                                         __ATOMIC_RELAXED, __HIP_MEMORY_SCOPE_AGENT);
  const uint64_t phi = __hip_atomic_load((const uint64_t*)(Pc + 8),
                                         __ATOMIC_RELAXED, __HIP_MEMORY_SCOPE_AGENT);

#pragma unroll
  for (int k = 0; k < GITER; ++k) {
    const int b = b0 + 2 * k;
    const uint32_t byte = (uint32_t)((k < 8 ? plo : phi) >> (8 * (k & 7))) & 0xFFu;
    const size_t row = ((size_t)b * NI + i) << 12;
    const float* xb = x + row;
    float4 o;
    o.x = xb[(int)( byte       & 3u) + t + 0 - 1];
    o.y = xb[(int)((byte >> 2) & 3u) + t + 1 - 1];
    o.z = xb[(int)((byte >> 4) & 3u) + t + 2 - 1];
    o.w = xb[(int)((byte >> 6) & 3u) + t + 3 - 1];
    *(float4*)(out + row + t) = o;
  }
}

// ---------------------------------------------------------------------------
extern "C" void kernel_launch(void* const* d_in, const int* in_sizes, int n_in,
                              void* d_out, int out_size, void* d_ws, size_t ws_size,
                              hipStream_t stream) {
  const float* x = (const float*)d_in[0];
  float* out = (float*)d_out;

  uint8_t* ws = (uint8_t*)d_ws;
  uint32_t* sab32 = (uint32_t*)ws;               // 32*4096*4 = 524288 B
  uint8_t*  P     = ws + 524288;                 // NCOPY*32768 = 262144 B

  const double pd = 0.1, sd = 1.0 - 2.0 * 0.1;
  const float pf = (float)pd, sf = (float)sd;
  const float b1 = (float)(sd / (pd + sd));
  const float b2 = (float)(pd / (pd + sd));
  const float LP  = (float)log((double)pf);
  const float LS  = (float)log((double)sf);
  const float LB1 = (float)log((double)b1);
  const float LB2 = (float)log((double)b2);

  dim3 g1((NSTEPS + 255) / 256, NB);
  k_sab<<<g1, 256, 0, stream>>>(sab32, LP, LS, LB1, LB2);
  k_scan<<<NB, THR, 0, stream>>>(sab32, P);
  k_gather<<<GBLK, 256, 0, stream>>>(x, P, out);
}

// Round 9
// 120.466 us; speedup vs baseline: 1.5709x; 1.3271x over previous
//
#include <hip/hip_runtime.h>
#include <cmath>
#include <cstdint>

#define NB 32
#define NI 512
#define NT 4096
#define NSTEPS (NT - 2)   // 4094
#define THR 512           // threads per k_scan block
#define SPT 8             // steps per thread (512*8 = 4096 >= 4094)
#define GBLK 4096         // k_gather grid (flat linear sweep)
#define GITER 16          // quads per thread: 16.7M / (4096*256)

// ---------------------------------------------------------------------------
// JAX threefry2x32 (20 rounds), matches jax/_src/prng.py exactly.
// Verified bit-exact on hardware (rounds 1-8: absmax 0.0).
// ---------------------------------------------------------------------------
__device__ __forceinline__ uint32_t rotl32(uint32_t v, unsigned d) {
  return (v << d) | (v >> (32u - d));
}

__device__ __forceinline__ void threefry2x32(uint32_t k0, uint32_t k1,
                                             uint32_t& x0, uint32_t& x1) {
  const uint32_t k2 = k0 ^ k1 ^ 0x1BD11BDAu;
  x0 += k0; x1 += k1;
#define TF_R(rot) { x0 += x1; x1 = rotl32(x1, rot); x1 ^= x0; }
  TF_R(13) TF_R(15) TF_R(26) TF_R(6)
  x0 += k1; x1 += k2 + 1u;
  TF_R(17) TF_R(29) TF_R(16) TF_R(24)
  x0 += k2; x1 += k0 + 2u;
  TF_R(13) TF_R(15) TF_R(26) TF_R(6)
  x0 += k0; x1 += k1 + 3u;
  TF_R(17) TF_R(29) TF_R(16) TF_R(24)
  x0 += k1; x1 += k2 + 4u;
  TF_R(13) TF_R(15) TF_R(26) TF_R(6)
  x0 += k2; x1 += k0 + 5u;
#undef TF_R
}

// uniform(minval=tiny,maxval=1) -> gumbel, f32 rounding after each log
// (emulated via correctly-rounded double log). Verified bit-exact.
__device__ __forceinline__ float gumbel_from_bits(uint32_t bits) {
  uint32_t fb = (bits >> 9) | 0x3F800000u;
  float f = __uint_as_float(fb) - 1.0f;          // [0, 1)
  float u = fmaxf(f, __FLT_MIN__);               // jnp.finfo(f32).tiny
  float lg = (float)log((double)u);
  return -(float)log((double)(-lg));
}

// ---------------------------------------------------------------------------
// 4-state chain encoding: 0:(p1=0) 1:(p1=1) 2:(p1=2,spec=0) 3:(p1=2,spec=1).
// Step: s = (st==3) ? sB : sA;  st' = (st==1 && s==2) ? 3 : s.
// ---------------------------------------------------------------------------
__device__ __forceinline__ uint32_t comp_map(uint32_t a, uint32_t b) {
  uint32_t r = 0;
#pragma unroll
  for (int st = 0; st < 4; ++st) {
    uint32_t as = (a >> (2 * st)) & 3u;
    uint32_t bs = (b >> (2 * as)) & 3u;
    r |= bs << (2 * st);
  }
  return r;
}

// ---------------------------------------------------------------------------
// K1: per (t,b) sample pair via partitionable threefry split + gumbel argmax.
// AGENT-scope stores (cross-XCD visibility under graph replay — round-1
// lesson). Spread over ALL CUs (round-3 lesson). ~3 us with k_scan.
// ---------------------------------------------------------------------------
__global__ void k_sab(uint32_t* __restrict__ sab32,
                      float LP, float LS, float LB1, float LB2) {
  int t = blockIdx.x * blockDim.x + threadIdx.x;
  int b = blockIdx.y;
  if (t >= NSTEPS) return;
  uint32_t k0 = 0u, k1 = (uint32_t)t;
  threefry2x32(0u, 42u, k0, k1);                 // key_t
  float g[3];
#pragma unroll
  for (int j = 0; j < 3; ++j) {
    uint32_t x0 = 0u, x1 = (uint32_t)(3 * b + j);
    threefry2x32(k0, k1, x0, x1);
    g[j] = gumbel_from_bits(x0 ^ x1);
  }
  float vA0 = LP + g[0], vA1 = LS + g[1], vA2 = LP + g[2];
  int sA = 0; float m = vA0;
  if (vA1 > m) { m = vA1; sA = 1; }
  if (vA2 > m) { sA = 2; }
  int sB = (LB2 + g[2] > LB1 + g[1]) ? 2 : 1;    // j=0 logit is -inf
  uint32_t v = (uint32_t)(sA | (sB << 4));
  __hip_atomic_store(&sab32[(size_t)b * NT + t], v,
                     __ATOMIC_RELAXED, __HIP_MEMORY_SCOPE_AGENT);
}

// ---------------------------------------------------------------------------
// K2: one block per batch — 4-state function-composition scan (9 LDS rounds),
// replay, cooperative AGENT-scope stores of packed m words. (Round-4 form.)
// ---------------------------------------------------------------------------
__global__ void __launch_bounds__(THR) k_scan(uint32_t* __restrict__ sab32,
                                              uint32_t* __restrict__ mword) {
  const int b = blockIdx.x;
  const int tid = threadIdx.x;

  __shared__ uint32_t smap[THR];
  __shared__ uint8_t lds_m[NT];

  // ---- load my SPT sab entries (pack nibbles) ----
  uint32_t packA = 0, packB = 0;
  const uint32_t* src = sab32 + (size_t)b * NT;
#pragma unroll
  for (int k = 0; k < SPT; ++k) {
    int t = tid * SPT + k;
    if (t >= NSTEPS) break;
    uint32_t w = __hip_atomic_load(&src[t], __ATOMIC_RELAXED,
                                   __HIP_MEMORY_SCOPE_AGENT);
    packA |= (w & 0xFu) << (4 * k);
    packB |= ((w >> 4) & 0xFu) << (4 * k);
  }

  // ---- build my chunk map ----
  uint32_t cmap;
  {
    uint32_t st0 = 0, st1 = 1, st2 = 2, st3 = 3;
#pragma unroll
    for (int k = 0; k < SPT; ++k) {
      int t = tid * SPT + k;
      if (t >= NSTEPS) break;
      uint32_t sA = (packA >> (4 * k)) & 0xFu;
      uint32_t sB = (packB >> (4 * k)) & 0xFu;
#define STEP(st) { uint32_t s = (st == 3u) ? sB : sA; st = (st == 1u && s == 2u) ? 3u : s; }
      STEP(st0) STEP(st1) STEP(st2) STEP(st3)
#undef STEP
    }
    cmap = st0 | (st1 << 2) | (st2 << 4) | (st3 << 6);
  }
  smap[tid] = cmap;
  __syncthreads();
  for (int d = 1; d < THR; d <<= 1) {
    uint32_t prev = (tid >= d) ? smap[tid - d] : 0u;
    __syncthreads();
    if (tid >= d) smap[tid] = comp_map(prev, smap[tid]);
    __syncthreads();
  }
  uint32_t st = (tid == 0) ? 1u : ((smap[tid - 1] >> 2) & 3u);

  // ---- replay, write m bytes ----
#pragma unroll
  for (int k = 0; k < SPT; ++k) {
    int t = tid * SPT + k;
    if (t >= NSTEPS) break;
    uint32_t sA = (packA >> (4 * k)) & 0xFu;
    uint32_t sB = (packB >> (4 * k)) & 0xFu;
    uint32_t s = (st == 3u) ? sB : sA;
    st = (st == 1u && s == 2u) ? 3u : s;
    lds_m[t + 1] = (uint8_t)s;
  }
  if (tid == 0) lds_m[0] = 1;
  if (tid == THR - 1) lds_m[NT - 1] = 1;
  __syncthreads();

  const uint32_t* wsrc = (const uint32_t*)lds_m;
  uint32_t* dst = mword + (size_t)b * (NT / 4);
#pragma unroll
  for (int r = 0; r < (NT / 4) / THR; ++r) {
    int w = r * THR + tid;
    __hip_atomic_store(&dst[w], wsrc[w],
                       __ATOMIC_RELAXED, __HIP_MEMORY_SCOPE_AGENT);
  }
}

// ---------------------------------------------------------------------------
// K3: gather out[b,i,t] = x[b,i, m[b,t] + t - 1].
// Round-4 structure (flat linear sweep, per-thread, IN-LOOP index loads —
// rounds 5/6/7/8 lesson: any variant that hoists the index loads out of the
// loop lets waves race ahead and interleave 16 distant DRAM windows,
// dropping effective BW from 4.7 to ~2.5 TB/s. The in-loop load phase-locks
// all waves into one contiguous sweep window).
// New vs round 4: explicit DEPTH-2 SOFTWARE PIPELINE — issue iteration k+1's
// mword agent-load before iteration k's x-loads, so the ~800-cycle
// coherence-point latency hides behind the current window's x-traffic while
// staying at most ONE window ahead. #pragma unroll 1 pins the schedule
// (full unroll would let the compiler re-hoist all 16 loads = round-8 mode).
// ---------------------------------------------------------------------------
__global__ void __launch_bounds__(256) k_gather(const float* __restrict__ x,
                                                uint32_t* __restrict__ mword,
                                                float* __restrict__ out) {
  const int q0  = blockIdx.x * 256 + threadIdx.x;
  const int b0  = q0 >> 19;                      // 0 or 1; b_k = b0 + 2k
  const int rem = q0 & ((1 << 19) - 1);          // const over k
  const int i   = rem >> 10;
  const int w   = rem & 1023;
  const int t   = w << 2;

  const size_t mbase = ((size_t)b0 << 10) | (uint32_t)w;
  const size_t rowstep = ((size_t)2 * NI) << 12;            // 2 batches of x
  size_t row = ((size_t)b0 * NI + i) << 12;

  uint32_t mw = __hip_atomic_load(&mword[mbase], __ATOMIC_RELAXED,
                                  __HIP_MEMORY_SCOPE_AGENT);
#pragma unroll 1
  for (int k = 0; k < GITER; ++k) {
    uint32_t mw_next = 0u;
    if (k + 1 < GITER) {
      mw_next = __hip_atomic_load(&mword[mbase + ((size_t)(2 * (k + 1)) << 10)],
                                  __ATOMIC_RELAXED, __HIP_MEMORY_SCOPE_AGENT);
    }
    const float* xb = x + row;
    float4 o;
    o.x = xb[(int)( mw        & 0xFFu) + t + 0 - 1];
    o.y = xb[(int)((mw >>  8) & 0xFFu) + t + 1 - 1];
    o.z = xb[(int)((mw >> 16) & 0xFFu) + t + 2 - 1];
    o.w = xb[(int)((mw >> 24) & 0xFFu) + t + 3 - 1];
    *(float4*)(out + row + t) = o;
    mw = mw_next;
    row += rowstep;
  }
}

// ---------------------------------------------------------------------------
extern "C" void kernel_launch(void* const* d_in, const int* in_sizes, int n_in,
                              void* d_out, int out_size, void* d_ws, size_t ws_size,
                              hipStream_t stream) {
  const float* x = (const float*)d_in[0];
  float* out = (float*)d_out;

  uint8_t* ws = (uint8_t*)d_ws;
  uint32_t* sab32 = (uint32_t*)ws;               // 32*4096*4 = 524288 B
  uint32_t* mword = (uint32_t*)(ws + 524288);    // 32*1024*4 = 131072 B

  const double pd = 0.1, sd = 1.0 - 2.0 * 0.1;
  const float pf = (float)pd, sf = (float)sd;
  const float b1 = (float)(sd / (pd + sd));
  const float b2 = (float)(pd / (pd + sd));
  const float LP  = (float)log((double)pf);
  const float LS  = (float)log((double)sf);
  const float LB1 = (float)log((double)b1);
  const float LB2 = (float)log((double)b2);

  dim3 g1((NSTEPS + 255) / 256, NB);
  k_sab<<<g1, 256, 0, stream>>>(sab32, LP, LS, LB1, LB2);
  k_scan<<<NB, THR, 0, stream>>>(sab32, mword);
  k_gather<<<GBLK, 256, 0, stream>>>(x, mword, out);
}

// Round 10
// 119.913 us; speedup vs baseline: 1.5781x; 1.0046x over previous
//
#include <hip/hip_runtime.h>
#include <cmath>
#include <cstdint>

#define NB 32
#define NI 512
#define NT 4096
#define NSTEPS (NT - 2)   // 4094
#define THR 512           // threads per k_scan block
#define SPT 8             // steps per thread (512*8 = 4096 >= 4094)
#define GBLK 4096         // k_gather grid (flat linear sweep)
#define GITER 16          // quads per thread: 16.7M / (4096*256)

// ---------------------------------------------------------------------------
// JAX threefry2x32 (20 rounds), matches jax/_src/prng.py exactly.
// Verified bit-exact on hardware (rounds 1-9: absmax 0.0).
// ---------------------------------------------------------------------------
__device__ __forceinline__ uint32_t rotl32(uint32_t v, unsigned d) {
  return (v << d) | (v >> (32u - d));
}

__device__ __forceinline__ void threefry2x32(uint32_t k0, uint32_t k1,
                                             uint32_t& x0, uint32_t& x1) {
  const uint32_t k2 = k0 ^ k1 ^ 0x1BD11BDAu;
  x0 += k0; x1 += k1;
#define TF_R(rot) { x0 += x1; x1 = rotl32(x1, rot); x1 ^= x0; }
  TF_R(13) TF_R(15) TF_R(26) TF_R(6)
  x0 += k1; x1 += k2 + 1u;
  TF_R(17) TF_R(29) TF_R(16) TF_R(24)
  x0 += k2; x1 += k0 + 2u;
  TF_R(13) TF_R(15) TF_R(26) TF_R(6)
  x0 += k0; x1 += k1 + 3u;
  TF_R(17) TF_R(29) TF_R(16) TF_R(24)
  x0 += k1; x1 += k2 + 4u;
  TF_R(13) TF_R(15) TF_R(26) TF_R(6)
  x0 += k2; x1 += k0 + 5u;
#undef TF_R
}

// uniform(minval=tiny,maxval=1) -> gumbel, f32 rounding after each log
// (emulated via correctly-rounded double log). Verified bit-exact.
__device__ __forceinline__ float gumbel_from_bits(uint32_t bits) {
  uint32_t fb = (bits >> 9) | 0x3F800000u;
  float f = __uint_as_float(fb) - 1.0f;          // [0, 1)
  float u = fmaxf(f, __FLT_MIN__);               // jnp.finfo(f32).tiny
  float lg = (float)log((double)u);
  return -(float)log((double)(-lg));
}

// ---------------------------------------------------------------------------
// 4-state chain encoding: 0:(p1=0) 1:(p1=1) 2:(p1=2,spec=0) 3:(p1=2,spec=1).
// Step: s = (st==3) ? sB : sA;  st' = (st==1 && s==2) ? 3 : s.
// ---------------------------------------------------------------------------
__device__ __forceinline__ uint32_t comp_map(uint32_t a, uint32_t b) {
  uint32_t r = 0;
#pragma unroll
  for (int st = 0; st < 4; ++st) {
    uint32_t as = (a >> (2 * st)) & 3u;
    uint32_t bs = (b >> (2 * as)) & 3u;
    r |= bs << (2 * st);
  }
  return r;
}

// ---------------------------------------------------------------------------
// K1: per (t,b) sample pair via partitionable threefry split + gumbel argmax.
// AGENT-scope stores (cross-XCD visibility under graph replay — round-1
// lesson). Spread over ALL CUs (round-3 lesson). ~3 us with k_scan.
// ---------------------------------------------------------------------------
__global__ void k_sab(uint32_t* __restrict__ sab32,
                      float LP, float LS, float LB1, float LB2) {
  int t = blockIdx.x * blockDim.x + threadIdx.x;
  int b = blockIdx.y;
  if (t >= NSTEPS) return;
  uint32_t k0 = 0u, k1 = (uint32_t)t;
  threefry2x32(0u, 42u, k0, k1);                 // key_t
  float g[3];
#pragma unroll
  for (int j = 0; j < 3; ++j) {
    uint32_t x0 = 0u, x1 = (uint32_t)(3 * b + j);
    threefry2x32(k0, k1, x0, x1);
    g[j] = gumbel_from_bits(x0 ^ x1);
  }
  float vA0 = LP + g[0], vA1 = LS + g[1], vA2 = LP + g[2];
  int sA = 0; float m = vA0;
  if (vA1 > m) { m = vA1; sA = 1; }
  if (vA2 > m) { sA = 2; }
  int sB = (LB2 + g[2] > LB1 + g[1]) ? 2 : 1;    // j=0 logit is -inf
  uint32_t v = (uint32_t)(sA | (sB << 4));
  __hip_atomic_store(&sab32[(size_t)b * NT + t], v,
                     __ATOMIC_RELAXED, __HIP_MEMORY_SCOPE_AGENT);
}

// ---------------------------------------------------------------------------
// K2: one block per batch — 4-state function-composition scan (9 LDS rounds),
// replay, cooperative AGENT-scope stores of packed m words. (Round-4 form.)
// ---------------------------------------------------------------------------
__global__ void __launch_bounds__(THR) k_scan(uint32_t* __restrict__ sab32,
                                              uint32_t* __restrict__ mword) {
  const int b = blockIdx.x;
  const int tid = threadIdx.x;

  __shared__ uint32_t smap[THR];
  __shared__ uint8_t lds_m[NT];

  // ---- load my SPT sab entries (pack nibbles) ----
  uint32_t packA = 0, packB = 0;
  const uint32_t* src = sab32 + (size_t)b * NT;
#pragma unroll
  for (int k = 0; k < SPT; ++k) {
    int t = tid * SPT + k;
    if (t >= NSTEPS) break;
    uint32_t w = __hip_atomic_load(&src[t], __ATOMIC_RELAXED,
                                   __HIP_MEMORY_SCOPE_AGENT);
    packA |= (w & 0xFu) << (4 * k);
    packB |= ((w >> 4) & 0xFu) << (4 * k);
  }

  // ---- build my chunk map ----
  uint32_t cmap;
  {
    uint32_t st0 = 0, st1 = 1, st2 = 2, st3 = 3;
#pragma unroll
    for (int k = 0; k < SPT; ++k) {
      int t = tid * SPT + k;
      if (t >= NSTEPS) break;
      uint32_t sA = (packA >> (4 * k)) & 0xFu;
      uint32_t sB = (packB >> (4 * k)) & 0xFu;
#define STEP(st) { uint32_t s = (st == 3u) ? sB : sA; st = (st == 1u && s == 2u) ? 3u : s; }
      STEP(st0) STEP(st1) STEP(st2) STEP(st3)
#undef STEP
    }
    cmap = st0 | (st1 << 2) | (st2 << 4) | (st3 << 6);
  }
  smap[tid] = cmap;
  __syncthreads();
  for (int d = 1; d < THR; d <<= 1) {
    uint32_t prev = (tid >= d) ? smap[tid - d] : 0u;
    __syncthreads();
    if (tid >= d) smap[tid] = comp_map(prev, smap[tid]);
    __syncthreads();
  }
  uint32_t st = (tid == 0) ? 1u : ((smap[tid - 1] >> 2) & 3u);

  // ---- replay, write m bytes ----
#pragma unroll
  for (int k = 0; k < SPT; ++k) {
    int t = tid * SPT + k;
    if (t >= NSTEPS) break;
    uint32_t sA = (packA >> (4 * k)) & 0xFu;
    uint32_t sB = (packB >> (4 * k)) & 0xFu;
    uint32_t s = (st == 3u) ? sB : sA;
    st = (st == 1u && s == 2u) ? 3u : s;
    lds_m[t + 1] = (uint8_t)s;
  }
  if (tid == 0) lds_m[0] = 1;
  if (tid == THR - 1) lds_m[NT - 1] = 1;
  __syncthreads();

  const uint32_t* wsrc = (const uint32_t*)lds_m;
  uint32_t* dst = mword + (size_t)b * (NT / 4);
#pragma unroll
  for (int r = 0; r < (NT / 4) / THR; ++r) {
    int w = r * THR + tid;
    __hip_atomic_store(&dst[w], wsrc[w],
                       __ATOMIC_RELAXED, __HIP_MEMORY_SCOPE_AGENT);
  }
}

// ---------------------------------------------------------------------------
// K3: gather out[b,i,t] = x[b,i, m[b,t] + t - 1].
// Flat linear sweep + in-loop depth-2 index pipeline (round-9 passing form).
// NEW: VECTORIZED READ SIDE. m+t-1 ∈ {t-1,t,t+1}, so the 4 outputs select
// from the window [t-1, t+4] = own aligned float4 q plus one element from
// each neighbor lane's quad — fetched via __shfl_up/__shfl_down instead of
// 4 scalar dword loads (rounds 4-9 lesson: gather is VMEM-issue bound, not
// HBM-BW bound; read side was 4 instrs x 16 lines per wave-iter).
// Lane 0 / lane 63 edges: predicated scalar dword (1-2 lines). The w==0 and
// w==1023 row edges never select prev/next (m forced to 1 at both row ends
// by construction), so no OOB and no correctness edge.
// ---------------------------------------------------------------------------
__global__ void __launch_bounds__(256) k_gather(const float* __restrict__ x,
                                                uint32_t* __restrict__ mword,
                                                float* __restrict__ out) {
  const int tid = threadIdx.x;
  const int q0  = blockIdx.x * 256 + tid;
  const int b0  = q0 >> 19;                      // 0 or 1; b_k = b0 + 2k
  const int rem = q0 & ((1 << 19) - 1);          // const over k
  const int i   = rem >> 10;
  const int w   = rem & 1023;
  const int t   = w << 2;
  const int lane = tid & 63;

  const size_t mbase = ((size_t)b0 << 10) | (uint32_t)w;
  const size_t rowstep = ((size_t)2 * NI) << 12;            // 2 batches of x
  size_t row = ((size_t)b0 * NI + i) << 12;

  const bool ld_lo = (lane == 0)  && (w > 0);
  const bool ld_hi = (lane == 63) && (w < 1023);

  uint32_t mw = __hip_atomic_load(&mword[mbase], __ATOMIC_RELAXED,
                                  __HIP_MEMORY_SCOPE_AGENT);
#pragma unroll 1
  for (int k = 0; k < GITER; ++k) {
    uint32_t mw_next = 0u;
    if (k + 1 < GITER) {
      mw_next = __hip_atomic_load(&mword[mbase + ((size_t)(2 * (k + 1)) << 10)],
                                  __ATOMIC_RELAXED, __HIP_MEMORY_SCOPE_AGENT);
    }
    const float* xb = x + row;
    const float4 q = *(const float4*)(xb + t);

    // wave-boundary edge elements (rarely-active masked loads)
    float edge_lo = 0.0f, edge_hi = 0.0f;
    if (ld_lo) edge_lo = xb[t - 1];
    if (ld_hi) edge_hi = xb[t + 4];

    float prev = __shfl_up(q.w, 1);              // lane l-1's element t-1
    if (lane == 0) prev = edge_lo;
    float next = __shfl_down(q.x, 1);            // lane l+1's element t+4
    if (lane == 63) next = edge_hi;

    const uint32_t m0 =  mw        & 0xFFu;
    const uint32_t m1 = (mw >>  8) & 0xFFu;
    const uint32_t m2 = (mw >> 16) & 0xFFu;
    const uint32_t m3 = (mw >> 24) & 0xFFu;

    float4 o;
    o.x = (m0 == 0u) ? prev : ((m0 == 1u) ? q.x : q.y);
    o.y = (m1 == 0u) ? q.x  : ((m1 == 1u) ? q.y : q.z);
    o.z = (m2 == 0u) ? q.y  : ((m2 == 1u) ? q.z : q.w);
    o.w = (m3 == 0u) ? q.z  : ((m3 == 1u) ? q.w : next);
    *(float4*)(out + row + t) = o;

    mw = mw_next;
    row += rowstep;
  }
}

// ---------------------------------------------------------------------------
extern "C" void kernel_launch(void* const* d_in, const int* in_sizes, int n_in,
                              void* d_out, int out_size, void* d_ws, size_t ws_size,
                              hipStream_t stream) {
  const float* x = (const float*)d_in[0];
  float* out = (float*)d_out;

  uint8_t* ws = (uint8_t*)d_ws;
  uint32_t* sab32 = (uint32_t*)ws;               // 32*4096*4 = 524288 B
  uint32_t* mword = (uint32_t*)(ws + 524288);    // 32*1024*4 = 131072 B

  const double pd = 0.1, sd = 1.0 - 2.0 * 0.1;
  const float pf = (float)pd, sf = (float)sd;
  const float b1 = (float)(sd / (pd + sd));
  const float b2 = (float)(pd / (pd + sd));
  const float LP  = (float)log((double)pf);
  const float LS  = (float)log((double)sf);
  const float LB1 = (float)log((double)b1);
  const float LB2 = (float)log((double)b2);

  dim3 g1((NSTEPS + 255) / 256, NB);
  k_sab<<<g1, 256, 0, stream>>>(sab32, LP, LS, LB1, LB2);
  k_scan<<<NB, THR, 0, stream>>>(sab32, mword);
  k_gather<<<GBLK, 256, 0, stream>>>(x, mword, out);
}